// Round 11
// baseline (557.498 us; speedup 1.0000x reference)
//
#include <hip/hip_runtime.h>

#define BATCH 256
#define SEQ   128
#define EDIM  300
#define PDIM  200
#define BSTOK (BATCH * SEQ)

#define F_RELU  1
#define F_ACCUM 2

typedef unsigned short u16;
typedef __attribute__((ext_vector_type(8))) short bf16x8;
typedef __attribute__((ext_vector_type(4))) float f32x4;

__device__ __forceinline__ u16 f2bf(float x) {
    unsigned u = __float_as_uint(x);
    unsigned r = u + 0x7fffu + ((u >> 16) & 1u);
    return (u16)(r >> 16);
}
__device__ __forceinline__ float bf2f(u16 h) {
    return __uint_as_float(((unsigned)h) << 16);
}

// split 16 fp32 -> hi(trunc)/lo(residual) bf16, store 2 x uint4 each.
__device__ __forceinline__ void split_store(const float* va, u16* dH, u16* dL)
{
    unsigned hp[8], lp[8];
    #pragma unroll
    for (int i = 0; i < 8; i++) {
        const unsigned u0 = __float_as_uint(va[2 * i]);
        const unsigned u1 = __float_as_uint(va[2 * i + 1]);
        const unsigned h0 = u0 & 0xffff0000u;
        const unsigned h1 = u1 & 0xffff0000u;
        hp[i] = (u0 >> 16) | h1;
        const float r0 = va[2 * i]     - __uint_as_float(h0);
        const float r1 = va[2 * i + 1] - __uint_as_float(h1);
        lp[i] = (__float_as_uint(r0) >> 16) | (__float_as_uint(r1) & 0xffff0000u);
    }
    ((uint4*)dH)[0] = make_uint4(hp[0], hp[1], hp[2], hp[3]);
    ((uint4*)dH)[1] = make_uint4(hp[4], hp[5], hp[6], hp[7]);
    ((uint4*)dL)[0] = make_uint4(lp[0], lp[1], lp[2], lp[3]);
    ((uint4*)dL)[1] = make_uint4(lp[4], lp[5], lp[6], lp[7]);
}

// RNE-rounded hi-only store (for 1-MFMA paths).
__device__ __forceinline__ void hi_store(const float* va, u16* dH)
{
    unsigned hp[8];
    #pragma unroll
    for (int i = 0; i < 8; i++)
        hp[i] = (unsigned)f2bf(va[2 * i]) | ((unsigned)f2bf(va[2 * i + 1]) << 16);
    ((uint4*)dH)[0] = make_uint4(hp[0], hp[1], hp[2], hp[3]);
    ((uint4*)dH)[1] = make_uint4(hp[4], hp[5], hp[6], hp[7]);
}

__device__ __forceinline__ void load16(float* va, const float* __restrict__ src,
                                       bool row_ok, int kbase, int Kvalid)
{
    if (row_ok) {
        #pragma unroll
        for (int i = 0; i < 4; i++) {
            const float4 v = *(const float4*)(src + i * 4);
            va[i * 4 + 0] = v.x; va[i * 4 + 1] = v.y;
            va[i * 4 + 2] = v.z; va[i * 4 + 3] = v.w;
        }
        #pragma unroll
        for (int i = 0; i < 16; i++)
            va[i] = (kbase + i < Kvalid) ? va[i] : 0.f;
    } else {
        #pragma unroll
        for (int i = 0; i < 16; i++) va[i] = 0.f;
    }
}

__device__ __forceinline__ void stage16(const float* __restrict__ src, bool row_ok,
                                        int kbase, int Kvalid, u16* dH, u16* dL)
{
    float va[16];
    load16(va, src, row_ok, kbase, Kvalid);
    split_store(va, dH, dL);
}

__device__ __forceinline__ void stage16_hi(const float* __restrict__ src, bool row_ok,
                                           int kbase, int Kvalid, u16* dH)
{
    float va[16];
    load16(va, src, row_ok, kbase, Kvalid);
    hi_store(va, dH);
}

// Straight u16 copy staging (pre-converted bf16 source, zero-padded rows).
__device__ __forceinline__ void stage16_u16(const u16* __restrict__ src, bool row_ok,
                                            u16* dH)
{
    uint4 a = make_uint4(0, 0, 0, 0), b = make_uint4(0, 0, 0, 0);
    if (row_ok) {
        a = *(const uint4*)(src);
        b = *(const uint4*)(src + 8);
    }
    ((uint4*)dH)[0] = a;
    ((uint4*)dH)[1] = b;
}

// Gathered-embedding: va = emb_row[kb..kb+15] * nrm, zero k >= 300.
__device__ __forceinline__ void gather16(float* va, const float* __restrict__ erow,
                                         float nrm, int kb)
{
    if (kb + 16 <= EDIM) {
        #pragma unroll
        for (int i = 0; i < 4; i++) {
            const float4 v = *(const float4*)(erow + kb + i * 4);
            va[i * 4 + 0] = v.x; va[i * 4 + 1] = v.y;
            va[i * 4 + 2] = v.z; va[i * 4 + 3] = v.w;
        }
    } else {
        #pragma unroll
        for (int i = 0; i < 16; i++)
            va[i] = (kb + i < EDIM) ? erow[kb + i] : 0.f;
    }
    #pragma unroll
    for (int i = 0; i < 16; i++) va[i] *= nrm;
}

__device__ __forceinline__ void stage_gather(const float* __restrict__ erow, float nrm,
                                             int kb, u16* dH, u16* dL)
{
    float va[16];
    gather16(va, erow, nrm, kb);
    split_store(va, dH, dL);
}

__device__ __forceinline__ void stage_gather_hi(const float* __restrict__ erow, float nrm,
                                                int kb, u16* dH)
{
    float va[16];
    gather16(va, erow, nrm, kb);
    hi_store(va, dH);
}

#define MFMA3(ai, aj) \
    acc[ai][aj] = __builtin_amdgcn_mfma_f32_16x16x32_bf16(fah[ai], fbh[aj], acc[ai][aj], 0, 0, 0); \
    acc[ai][aj] = __builtin_amdgcn_mfma_f32_16x16x32_bf16(fah[ai], fbl[aj], acc[ai][aj], 0, 0, 0); \
    acc[ai][aj] = __builtin_amdgcn_mfma_f32_16x16x32_bf16(fal[ai], fbh[aj], acc[ai][aj], 0, 0, 0);

#define MFMA1(ai, aj) \
    acc[ai][aj] = __builtin_amdgcn_mfma_f32_16x16x32_bf16(fah[ai], fbh[aj], acc[ai][aj], 0, 0, 0);

// Coalesced transposed store of the block's 128x128 tile via LDS (stride 129).
__device__ __forceinline__ void store_transposed(
    float* __restrict__ PT, const f32x4 (*acc)[4], float* TR,
    int bn, int Nvalid, int wm, int wn, int lr, int quad, int tid, bool relu)
{
    #pragma unroll
    for (int h = 0; h < 2; h++) {
        __syncthreads();
        if ((wn >> 6) == h) {
            #pragma unroll
            for (int j = 0; j < 4; j++) {
                const int col = j * 16 + lr;
                #pragma unroll
                for (int i = 0; i < 4; i++)
                    #pragma unroll
                    for (int r = 0; r < 4; r++) {
                        float v = acc[i][j][r];
                        if (relu) v = fmaxf(v, 0.f);
                        TR[col * 129 + wm + i * 16 + quad * 4 + r] = v;
                    }
            }
        }
        __syncthreads();
        const int row = tid >> 2;
        const int gp = bn + h * 64 + row;
        if (gp < Nvalid) {
            float* dst = PT + (long long)gp * 128;
            for (int c = (tid & 3); c < 32; c += 4) {
                const int base = row * 129 + c * 4;
                *(float4*)(dst + c * 4) =
                    make_float4(TR[base], TR[base + 1], TR[base + 2], TR[base + 3]);
            }
        }
    }
}

// ---------------------------------------------------------------------------
// Merged phase-A projection GEMM (both sides, grid (5, 512), XCD-swizzled):
//   bn < 256  -> T[mt][gn][.] (transposed coalesced, 3-MFMA: output-critical)
//   bn >= 256 -> Fside u16 RNE [32768][320] relu (1-MFMA: feeds att only;
//                cols 300:320 zeroed for copy-staged consumers)
// ---------------------------------------------------------------------------
__global__ __launch_bounds__(256) void gemm_proj(
    const int* __restrict__ x1, const int* __restrict__ x2,
    const float* __restrict__ emb, const float* __restrict__ norms,
    const u16* __restrict__ W1h, const u16* __restrict__ W1l,
    const u16* __restrict__ W2h, const u16* __restrict__ W2l,
    float* __restrict__ T, u16* __restrict__ F0, u16* __restrict__ F1)
{
    __shared__ __align__(16) unsigned char smem[40960];
    u16 (*AsH)[40] = (u16(*)[40])(smem);
    u16 (*AsL)[40] = (u16(*)[40])(smem + 10240);
    u16 (*BsH)[40] = (u16(*)[40])(smem + 20480);
    u16 (*BsL)[40] = (u16(*)[40])(smem + 30720);

    const int tid = threadIdx.x;
    const int id  = blockIdx.y * 5 + blockIdx.x;
    const int xcd = id & 7;
    const int s   = id >> 3;
    const int mt  = xcd + 8 * (s / 5);
    const int bm  = mt * 128;
    const int bn  = (s % 5) * 128;
    const bool side2 = mt >= 256;
    const bool wb = bn < 256;          // block-uniform precision tier

    const u16* Bh = side2 ? W2h : W1h;
    const u16* Bl = side2 ? W2l : W1l;
    u16* F = side2 ? F1 : F0;
    const int fm = side2 ? bm - 32768 : bm;
    const int* toks = (side2 ? x2 - 32768 : x1) + bm;

    const int wave = tid >> 6;
    const int lane = tid & 63;
    const int wm   = (wave >> 1) * 64;
    const int wn   = (wave & 1) * 64;
    const int lr   = lane & 15;
    const int quad = lane >> 4;
    const int sr   = tid >> 1;
    const int sc   = (tid & 1) * 16;

    const int tok = toks[sr];
    const float nrm = norms[tok];
    const float* erow = emb + (long long)tok * EDIM;

    f32x4 acc[4][4];
    #pragma unroll
    for (int i = 0; i < 4; i++)
        #pragma unroll
        for (int j = 0; j < 4; j++)
            acc[i][j] = (f32x4)(0.0f);

    for (int k0 = 0; k0 < 320; k0 += 32) {
        if (wb) stage_gather(erow, nrm, k0 + sc, &AsH[sr][sc], &AsL[sr][sc]);
        else    stage_gather_hi(erow, nrm, k0 + sc, &AsH[sr][sc]);
        {
            uint4 wh0 = make_uint4(0,0,0,0), wh1 = make_uint4(0,0,0,0);
            const int gn = bn + sr;
            const long long br = (long long)gn * 320 + k0 + sc;
            if (gn < 556) {
                wh0 = *(const uint4*)(Bh + br);
                wh1 = *(const uint4*)(Bh + br + 8);
            }
            *(uint4*)&BsH[sr][sc]     = wh0;
            *(uint4*)&BsH[sr][sc + 8] = wh1;
            if (wb) {
                uint4 wl0 = make_uint4(0,0,0,0), wl1 = make_uint4(0,0,0,0);
                if (gn < 556) {
                    wl0 = *(const uint4*)(Bl + br);
                    wl1 = *(const uint4*)(Bl + br + 8);
                }
                *(uint4*)&BsL[sr][sc]     = wl0;
                *(uint4*)&BsL[sr][sc + 8] = wl1;
            }
        }
        __syncthreads();

        bf16x8 fah[4], fal[4], fbh[4], fbl[4];
        #pragma unroll
        for (int i = 0; i < 4; i++) {
            fah[i] = *(const bf16x8*)&AsH[wm + i * 16 + lr][quad * 8];
            fbh[i] = *(const bf16x8*)&BsH[wn + i * 16 + lr][quad * 8];
        }
        if (wb) {
            #pragma unroll
            for (int i = 0; i < 4; i++) {
                fal[i] = *(const bf16x8*)&AsL[wm + i * 16 + lr][quad * 8];
                fbl[i] = *(const bf16x8*)&BsL[wn + i * 16 + lr][quad * 8];
            }
            #pragma unroll
            for (int i = 0; i < 4; i++)
                #pragma unroll
                for (int j = 0; j < 4; j++) { MFMA3(i, j) }
        } else {
            #pragma unroll
            for (int i = 0; i < 4; i++)
                #pragma unroll
                for (int j = 0; j < 4; j++) { MFMA1(i, j) }
        }
        __syncthreads();
    }

    if (wb) {
        float* Tb = T + (long long)mt * (PDIM * SEQ);
        store_transposed(Tb, acc, (float*)smem, bn, PDIM, wm, wn, lr, quad, tid, false);
    } else {
        #pragma unroll
        for (int i = 0; i < 4; i++) {
            #pragma unroll
            for (int j = 0; j < 4; j++) {
                const int idx = bn + wn + j * 16 + lr - 256;
                if (idx >= 320) continue;
                #pragma unroll
                for (int r = 0; r < 4; r++) {
                    const int gm = fm + wm + i * 16 + quad * 4 + r;
                    u16 o = 0;
                    if (idx < EDIM) o = f2bf(fmaxf(acc[i][j][r], 0.f));
                    F[(long long)gm * 320 + idx] = o;
                }
            }
        }
    }
}

// ---------------------------------------------------------------------------
// Fused xp GEMM (3-MFMA, output-critical): acc = e @ wp_a (K=320) +
// probs @ G (K=128); relu -> XCAT cols 0:200 + x_proj^T in-place over T.
// grid (2, 1, 512).
// ---------------------------------------------------------------------------
__global__ __launch_bounds__(256) void gemm_xp(
    const float* __restrict__ P, float* __restrict__ T,
    const int* __restrict__ x1, const int* __restrict__ x2,
    const float* __restrict__ emb, const float* __restrict__ norms,
    const u16* __restrict__ W1h, const u16* __restrict__ W1l,
    const u16* __restrict__ W2h, const u16* __restrict__ W2l,
    float* __restrict__ XCAT)
{
    __shared__ __align__(16) unsigned char smem[40960];
    u16 (*AsH)[40] = (u16(*)[40])(smem);
    u16 (*AsL)[40] = (u16(*)[40])(smem + 10240);
    u16 (*BsH)[40] = (u16(*)[40])(smem + 20480);
    u16 (*BsL)[40] = (u16(*)[40])(smem + 30720);

    const int tid = threadIdx.x;
    const int bz  = blockIdx.z;
    const int bn  = blockIdx.x * 128;

    const int wave = tid >> 6;
    const int lane = tid & 63;
    const int wm   = (wave >> 1) * 64;
    const int wn   = (wave & 1) * 64;
    const int lr   = lane & 15;
    const int quad = lane >> 4;
    const int sr   = tid >> 1;
    const int sc   = (tid & 1) * 16;

    const int* toks = (bz < BATCH) ? x1 + bz * SEQ : x2 + (bz - BATCH) * SEQ;
    const u16* Wh = (bz < BATCH) ? W1h : W2h;
    const u16* Wl = (bz < BATCH) ? W1l : W2l;
    const int tok = toks[sr];
    const float nrm = norms[tok];
    const float* erow = emb + (long long)tok * EDIM;
    const float* Pb = P + (long long)bz * (SEQ * SEQ);
    float* Tb = T + (long long)bz * (PDIM * SEQ);

    f32x4 acc[4][4];
    #pragma unroll
    for (int i = 0; i < 4; i++)
        #pragma unroll
        for (int j = 0; j < 4; j++)
            acc[i][j] = (f32x4)(0.0f);

    for (int k0 = 0; k0 < 320; k0 += 32) {
        stage_gather(erow, nrm, k0 + sc, &AsH[sr][sc], &AsL[sr][sc]);
        {
            uint4 wh0 = make_uint4(0,0,0,0), wh1 = make_uint4(0,0,0,0);
            uint4 wl0 = make_uint4(0,0,0,0), wl1 = make_uint4(0,0,0,0);
            const int gn = bn + sr;
            if (gn < PDIM) {
                const long long br = (long long)gn * 320 + k0 + sc;
                wh0 = *(const uint4*)(Wh + br);
                wh1 = *(const uint4*)(Wh + br + 8);
                wl0 = *(const uint4*)(Wl + br);
                wl1 = *(const uint4*)(Wl + br + 8);
            }
            *(uint4*)&BsH[sr][sc]     = wh0;
            *(uint4*)&BsH[sr][sc + 8] = wh1;
            *(uint4*)&BsL[sr][sc]     = wl0;
            *(uint4*)&BsL[sr][sc + 8] = wl1;
        }
        __syncthreads();

        bf16x8 fah[4], fal[4], fbh[4], fbl[4];
        #pragma unroll
        for (int i = 0; i < 4; i++) {
            fah[i] = *(const bf16x8*)&AsH[wm + i * 16 + lr][quad * 8];
            fal[i] = *(const bf16x8*)&AsL[wm + i * 16 + lr][quad * 8];
            fbh[i] = *(const bf16x8*)&BsH[wn + i * 16 + lr][quad * 8];
            fbl[i] = *(const bf16x8*)&BsL[wn + i * 16 + lr][quad * 8];
        }
        #pragma unroll
        for (int i = 0; i < 4; i++)
            #pragma unroll
            for (int j = 0; j < 4; j++) { MFMA3(i, j) }
        __syncthreads();
    }

    for (int k0 = 0; k0 < 128; k0 += 32) {
        stage16(Pb + (long long)sr * 128 + k0 + sc, true, 0, 1 << 30,
                &AsH[sr][sc], &AsL[sr][sc]);
        const int gn = bn + sr;
        stage16(Tb + (long long)gn * 128 + k0 + sc, gn < PDIM, 0, 1 << 30,
                &BsH[sr][sc], &BsL[sr][sc]);
        __syncthreads();

        bf16x8 fah[4], fal[4], fbh[4], fbl[4];
        #pragma unroll
        for (int i = 0; i < 4; i++) {
            fah[i] = *(const bf16x8*)&AsH[wm + i * 16 + lr][quad * 8];
            fal[i] = *(const bf16x8*)&AsL[wm + i * 16 + lr][quad * 8];
            fbh[i] = *(const bf16x8*)&BsH[wn + i * 16 + lr][quad * 8];
            fbl[i] = *(const bf16x8*)&BsL[wn + i * 16 + lr][quad * 8];
        }
        #pragma unroll
        for (int i = 0; i < 4; i++)
            #pragma unroll
            for (int j = 0; j < 4; j++) { MFMA3(i, j) }
        __syncthreads();
    }

    const long long rowbase = (long long)bz * SEQ;
    #pragma unroll
    for (int i = 0; i < 4; i++) {
        #pragma unroll
        for (int j = 0; j < 4; j++) {
            const int gn = bn + wn + j * 16 + lr;
            if (gn >= PDIM) continue;
            #pragma unroll
            for (int r = 0; r < 4; r++) {
                const int gm = wm + i * 16 + quad * 4 + r;
                XCAT[(rowbase + gm) * 400 + gn] = fmaxf(acc[i][j][r], 0.f);
            }
        }
    }
    store_transposed(Tb, acc, (float*)smem, bn, PDIM, wm, wn, lr, quad, tid, true);
}

// ---------------------------------------------------------------------------
// Flat MFMA GEMM vs pre-split transposed weights. NM = 3 (split) or 1 (bf16).
// XCD-swizzled when gridDim.y % 8 == 0. Per-m-tile weight select (Msplit).
// Outputs: fp32 C, u16 C16 (RNE, ld ldc16, zero-pad cols N..npad), pooled PO.
// ---------------------------------------------------------------------------
template <int NM>
__global__ __launch_bounds__(256) void gemm_flat(
    const float* __restrict__ A,
    const u16* __restrict__ Bh, const u16* __restrict__ Bl,
    const u16* __restrict__ Bh2, const u16* __restrict__ Bl2, int Msplit,
    float* __restrict__ C, u16* __restrict__ C16, int ldc16, int npad,
    float* __restrict__ PO, const int* __restrict__ sizes,
    int M, int N, int Kp, int lda, int ldb, int ldc, int flags)
{
    __shared__ u16 AsH[128][40];
    __shared__ u16 AsL[128][40];
    __shared__ u16 BsH[128][40];
    __shared__ u16 BsL[128][40];

    const int tid = threadIdx.x;
    int bx = blockIdx.x, by = blockIdx.y;
    if ((gridDim.y & 7) == 0) {
        const int gx = gridDim.x;
        const int id = by * gx + bx;
        const int xcd = id & 7;
        const int s = id >> 3;
        by = xcd + 8 * (s / gx);
        bx = s % gx;
    }
    const int bm = by * 128;
    const int bn = bx * 128;

    const int wave = tid >> 6;
    const int lane = tid & 63;
    const int wm   = (wave >> 1) * 64;
    const int wn   = (wave & 1) * 64;
    const int lr   = lane & 15;
    const int quad = lane >> 4;
    const int sr   = tid >> 1;
    const int sc   = (tid & 1) * 16;

    if (bm >= Msplit) { Bh = Bh2; Bl = Bl2; }

    f32x4 acc[4][4];
    #pragma unroll
    for (int i = 0; i < 4; i++)
        #pragma unroll
        for (int j = 0; j < 4; j++)
            acc[i][j] = (f32x4)(0.0f);

    for (int k0 = 0; k0 < Kp; k0 += 32) {
        if constexpr (NM == 3)
            stage16(A + (long long)(bm + sr) * lda + k0 + sc, true, 0, 1 << 30,
                    &AsH[sr][sc], &AsL[sr][sc]);
        else
            stage16_hi(A + (long long)(bm + sr) * lda + k0 + sc, true, 0, 1 << 30,
                       &AsH[sr][sc]);
        {
            uint4 wh0 = make_uint4(0,0,0,0), wh1 = make_uint4(0,0,0,0);
            const int gn = bn + sr;
            const long long br = (long long)gn * ldb + k0 + sc;
            if (gn < N) {
                wh0 = *(const uint4*)(Bh + br);
                wh1 = *(const uint4*)(Bh + br + 8);
            }
            *(uint4*)&BsH[sr][sc]     = wh0;
            *(uint4*)&BsH[sr][sc + 8] = wh1;
            if constexpr (NM == 3) {
                uint4 wl0 = make_uint4(0,0,0,0), wl1 = make_uint4(0,0,0,0);
                if (gn < N) {
                    wl0 = *(const uint4*)(Bl + br);
                    wl1 = *(const uint4*)(Bl + br + 8);
                }
                *(uint4*)&BsL[sr][sc]     = wl0;
                *(uint4*)&BsL[sr][sc + 8] = wl1;
            }
        }
        __syncthreads();

        bf16x8 fah[4], fal[4], fbh[4], fbl[4];
        #pragma unroll
        for (int i = 0; i < 4; i++) {
            fah[i] = *(const bf16x8*)&AsH[wm + i * 16 + lr][quad * 8];
            fbh[i] = *(const bf16x8*)&BsH[wn + i * 16 + lr][quad * 8];
        }
        if constexpr (NM == 3) {
            #pragma unroll
            for (int i = 0; i < 4; i++) {
                fal[i] = *(const bf16x8*)&AsL[wm + i * 16 + lr][quad * 8];
                fbl[i] = *(const bf16x8*)&BsL[wn + i * 16 + lr][quad * 8];
            }
            #pragma unroll
            for (int i = 0; i < 4; i++)
                #pragma unroll
                for (int j = 0; j < 4; j++) { MFMA3(i, j) }
        } else {
            #pragma unroll
            for (int i = 0; i < 4; i++)
                #pragma unroll
                for (int j = 0; j < 4; j++) { MFMA1(i, j) }
        }
        __syncthreads();
    }

    const int sz = PO ? sizes[bm >> 7] : 0;
    float ps[4] = {0.f, 0.f, 0.f, 0.f};
    #pragma unroll
    for (int j = 0; j < 4; j++) {
        const int gn = bn + wn + j * 16 + lr;
        const bool gok = gn < N;
        #pragma unroll
        for (int i = 0; i < 4; i++) {
            #pragma unroll
            for (int r = 0; r < 4; r++) {
                const int row = wm + i * 16 + quad * 4 + r;
                const int gm = bm + row;
                float v = acc[i][j][r];
                if (flags & F_RELU) v = fmaxf(v, 0.f);
                if (gok && C) C[(long long)gm * ldc + gn] = v;
                if (C16 && gn < npad) {
                    u16 o = gok ? f2bf(v) : (u16)0;
                    C16[(long long)gm * ldc16 + gn] = o;
                }
                if (PO && row < sz) ps[j] += v;
            }
        }
    }
    if (PO) {
        #pragma unroll
        for (int j = 0; j < 4; j++) {
            ps[j] += __shfl_xor(ps[j], 16);
            ps[j] += __shfl_xor(ps[j], 32);
        }
        float* PS = (float*)AsH;
        if (wm == 0 && quad == 0) {
            #pragma unroll
            for (int j = 0; j < 4; j++) PS[wn + j * 16 + lr] = ps[j];
        }
        __syncthreads();
        if (wm == 64 && quad == 0) {
            #pragma unroll
            for (int j = 0; j < 4; j++) PS[wn + j * 16 + lr] += ps[j];
        }
        __syncthreads();
        if (tid < 128) {
            const int gn = bn + tid;
            if (gn < N) PO[(long long)(bm >> 7) * N + gn] = PS[tid];
        }
    }
}

// ---------------------------------------------------------------------------
// Batched MFMA GEMM, NT. SRC16: operands are pre-converted bf16 (u16, zero-
// padded rows) staged by straight copy; else fp32 converted in staging.
// MODE 0 (3-MFMA): plain; ACCUM/RELU; optional sizes mask / PT store;
//         (Aalt,Balt) for bz>=256 with bz-256.
// MODE 1 (1-MFMA): att — dist-bias + fused row softmax -> C (probs).
// MODE 2 (1-MFMA): sim — mask + row softmax -> C + col softmax^T -> PT.
// ---------------------------------------------------------------------------
template <int MODE, bool SRC16>
__global__ __launch_bounds__(256) void gemm_bat(
    const void* __restrict__ A, const void* __restrict__ Aalt,
    const void* __restrict__ B, const void* __restrict__ Balt,
    float* __restrict__ C, float* __restrict__ PT,
    int N, int Kvalid, int Kp, int lda, int ldb, int ldc,
    long long sA, long long sB, long long sC, long long sPT,
    int flags, const float* __restrict__ bias_ptr, const int* __restrict__ sizes,
    int same_ab)
{
    constexpr int NM = (MODE == 0) ? 3 : 1;
    constexpr int SB = (MODE >= 1) ? 65536 : 40960;
    __shared__ __align__(16) unsigned char smem[SB];
    u16 (*AsH)[40] = (u16(*)[40])(smem);
    u16 (*AsL)[40] = (u16(*)[40])(smem + 10240);
    u16 (*BsH)[40] = (u16(*)[40])(smem + 20480);
    u16 (*BsL)[40] = (u16(*)[40])(smem + 30720);

    const int bz = blockIdx.z;
    long long zb = bz;
    const void* Araw = A;
    const void* Braw = B;
    if (Aalt && bz >= BATCH) { Araw = Aalt; Braw = Balt; zb = bz - BATCH; }
    C += (long long)bz * sC;
    if (PT) PT += (long long)bz * sPT;

    const int tid  = threadIdx.x;
    const int bn   = blockIdx.x * 128;
    const int wave = tid >> 6;
    const int lane = tid & 63;
    const int wm   = (wave >> 1) * 64;
    const int wn   = (wave & 1) * 64;
    const int lr   = lane & 15;
    const int quad = lane >> 4;
    const int sr   = tid >> 1;
    const int sc   = (tid & 1) * 16;

    f32x4 acc[4][4];
    #pragma unroll
    for (int i = 0; i < 4; i++)
        #pragma unroll
        for (int j = 0; j < 4; j++)
            acc[i][j] = (f32x4)(0.0f);

    u16 (*fbH)[40] = same_ab ? AsH : BsH;
    u16 (*fbL)[40] = same_ab ? AsL : BsL;

    for (int k0 = 0; k0 < Kp; k0 += 32) {
        if constexpr (SRC16) {
            const u16* A16 = (const u16*)Araw + zb * sA;
            stage16_u16(A16 + (long long)sr * lda + k0 + sc, true, &AsH[sr][sc]);
            if (!same_ab) {
                const u16* B16 = (const u16*)Braw + zb * sB;
                const int gn = bn + sr;
                stage16_u16(B16 + (long long)gn * ldb + k0 + sc, gn < N, &BsH[sr][sc]);
            }
        } else {
            const float* Af = (const float*)Araw + zb * sA;
            if constexpr (NM == 3)
                stage16(Af + (long long)sr * lda + k0 + sc, true, k0 + sc, Kvalid,
                        &AsH[sr][sc], &AsL[sr][sc]);
            else
                stage16_hi(Af + (long long)sr * lda + k0 + sc, true, k0 + sc, Kvalid,
                           &AsH[sr][sc]);
            if (!same_ab) {
                const float* Bf = (const float*)Braw + zb * sB;
                const int gn = bn + sr;
                if constexpr (NM == 3)
                    stage16(Bf + (long long)gn * ldb + k0 + sc, gn < N, k0 + sc, Kvalid,
                            &BsH[sr][sc], &BsL[sr][sc]);
                else
                    stage16_hi(Bf + (long long)gn * ldb + k0 + sc, gn < N, k0 + sc, Kvalid,
                               &BsH[sr][sc]);
            }
        }
        __syncthreads();

        bf16x8 fah[4], fal[4], fbh[4], fbl[4];
        #pragma unroll
        for (int i = 0; i < 4; i++) {
            fah[i] = *(const bf16x8*)&AsH[wm + i * 16 + lr][quad * 8];
            fbh[i] = *(const bf16x8*)&fbH[wn + i * 16 + lr][quad * 8];
        }
        if constexpr (NM == 3) {
            #pragma unroll
            for (int i = 0; i < 4; i++) {
                fal[i] = *(const bf16x8*)&AsL[wm + i * 16 + lr][quad * 8];
                fbl[i] = *(const bf16x8*)&fbL[wn + i * 16 + lr][quad * 8];
            }
            #pragma unroll
            for (int i = 0; i < 4; i++)
                #pragma unroll
                for (int j = 0; j < 4; j++) { MFMA3(i, j) }
        } else {
            #pragma unroll
            for (int i = 0; i < 4; i++)
                #pragma unroll
                for (int j = 0; j < 4; j++) { MFMA1(i, j) }
        }
        __syncthreads();
    }

    if (MODE == 1) {
        float* S = (float*)smem;
        const float bias = bias_ptr[0];
        #pragma unroll
        for (int i = 0; i < 4; i++) {
            #pragma unroll
            for (int j = 0; j < 4; j++) {
                const int col = wn + j * 16 + lr;
                #pragma unroll
                for (int r = 0; r < 4; r++) {
                    const int row = wm + i * 16 + quad * 4 + r;
                    int d = row - col; d = d < 0 ? -d : d;
                    S[row * 128 + col] = acc[i][j][r] + ((d >= 10) ? bias : 0.f);
                }
            }
        }
        __syncthreads();
        const int row = tid >> 1;
        const int half = (tid & 1) * 64;
        float mx = -1e30f;
        for (int c = 0; c < 64; c++) mx = fmaxf(mx, S[row * 128 + half + c]);
        mx = fmaxf(mx, __shfl_xor(mx, 1));
        float sum = 0.f;
        for (int c = 0; c < 64; c++) sum += __expf(S[row * 128 + half + c] - mx);
        sum += __shfl_xor(sum, 1);
        const float inv = 1.f / sum;
        for (int c = 0; c < 64; c++)
            C[(long long)row * ldc + half + c] = __expf(S[row * 128 + half + c] - mx) * inv;
    } else if (MODE == 2) {
        float* S = (float*)smem;
        const int s1 = sizes[bz];
        const int s2 = sizes[BATCH + bz];
        #pragma unroll
        for (int i = 0; i < 4; i++) {
            #pragma unroll
            for (int j = 0; j < 4; j++) {
                const int col = wn + j * 16 + lr;
                #pragma unroll
                for (int r = 0; r < 4; r++) {
                    const int row = wm + i * 16 + quad * 4 + r;
                    float v = acc[i][j][r];
                    if (row >= s1 || col >= s2) v = 0.f;
                    S[row * 128 + col] = v;
                }
            }
        }
        __syncthreads();
        const int idx = tid >> 1;
        const int half = (tid & 1) * 64;
        {
            float mx = -1e30f;
            for (int c = 0; c < 64; c++) mx = fmaxf(mx, S[idx * 128 + half + c]);
            mx = fmaxf(mx, __shfl_xor(mx, 1));
            float sum = 0.f;
            for (int c = 0; c < 64; c++) sum += __expf(S[idx * 128 + half + c] - mx);
            sum += __shfl_xor(sum, 1);
            const float inv = 1.f / sum;
            for (int c = 0; c < 64; c++)
                C[(long long)idx * 128 + half + c] = __expf(S[idx * 128 + half + c] - mx) * inv;
        }
        {
            float mx = -1e30f;
            for (int r = 0; r < 64; r++) mx = fmaxf(mx, S[(half + r) * 128 + idx]);
            mx = fmaxf(mx, __shfl_xor(mx, 1));
            float sum = 0.f;
            for (int r = 0; r < 64; r++) sum += __expf(S[(half + r) * 128 + idx] - mx);
            sum += __shfl_xor(sum, 1);
            const float inv = 1.f / sum;
            for (int r = 0; r < 64; r++)
                PT[(long long)idx * 128 + half + r] = __expf(S[(half + r) * 128 + idx] - mx) * inv;
        }
    } else {
        const int s1 = sizes ? sizes[bz] : SEQ;
        const int s2 = sizes ? sizes[BATCH + bz] : SEQ;
        #pragma unroll
        for (int i = 0; i < 4; i++) {
            #pragma unroll
            for (int j = 0; j < 4; j++) {
                const int gn = bn + wn + j * 16 + lr;
                if (gn >= N) continue;
                #pragma unroll
                for (int r = 0; r < 4; r++) {
                    const int gm = wm + i * 16 + quad * 4 + r;
                    float v = acc[i][j][r];
                    if (sizes && (gm >= s1 || gn >= s2)) v = 0.f;
                    if (flags & F_ACCUM) v += C[(long long)gm * ldc + gn];
                    if (flags & F_RELU)  v = fmaxf(v, 0.f);
                    C[(long long)gm * ldc + gn] = v;
                    if (PT) PT[(long long)gn * 128 + gm] = v;
                }
            }
        }
    }
}

// All weight transposes + hi/lo splits in one launch.
struct WEnt { const float* src; u16* H; u16* L; int K, N, Kp, rowStart; };
struct WTab { WEnt e[11]; };
__global__ void convert_all(WTab t)
{
    const int row = blockIdx.y;
    const int k = blockIdx.x * 256 + threadIdx.x;
    #pragma unroll
    for (int s = 0; s < 11; s++) {
        const WEnt w = t.e[s];
        if (row >= w.rowStart && row < w.rowStart + w.N) {
            const int n = row - w.rowStart;
            if (k < w.Kp) {
                const float v = (k < w.K) ? w.src[(long long)k * w.N + n] : 0.f;
                const u16 h = f2bf(v);
                w.H[(long long)n * w.Kp + k] = h;
                w.L[(long long)n * w.Kp + k] = f2bf(v - bf2f(h));
            }
            return;
        }
    }
}

__global__ void norms_kernel(const float* __restrict__ emb, float* __restrict__ norms)
{
    const int r = blockIdx.x;
    const int lane = threadIdx.x;
    const float* row = emb + (long long)r * EDIM;
    float ss = 0.f;
    #pragma unroll
    for (int i = 0; i < 5; i++) {
        const int c = lane + i * 64;
        const float f = (c < EDIM) ? row[c] : 0.f;
        ss += f * f;
    }
    #pragma unroll
    for (int o = 32; o > 0; o >>= 1) ss += __shfl_xor(ss, o);
    if (lane == 0) norms[r] = rsqrtf(fmaxf(ss, 1e-12f));
}

__global__ void sizes_kernel(const int* __restrict__ x1, const int* __restrict__ x2,
                             int* __restrict__ sizes)
{
    const int b = blockIdx.x;
    const int side = blockIdx.y;
    const int* x = (side ? x2 : x1) + b * SEQ;
    const int nz = (x[threadIdx.x] != 0) ? 1 : 0;
    const unsigned long long bal = __ballot(nz);
    __shared__ int part[2];
    if ((threadIdx.x & 63) == 0) part[threadIdx.x >> 6] = __popcll(bal);
    __syncthreads();
    if (threadIdx.x == 0) sizes[side * BATCH + b] = part[0] + part[1];
}

__global__ void agg_kernel(const float* __restrict__ v1s, const float* __restrict__ v2s,
                           const float* __restrict__ w_agg, float* __restrict__ y)
{
    const int b = blockIdx.x;
    const int lane = threadIdx.x;
    float a0 = 0.f, a1 = 0.f, a2 = 0.f;
    for (int k = lane; k < 800; k += 64) {
        const float v = (k < 400) ? v1s[b * 400 + k] : v2s[b * 400 + k - 400];
        a0 = fmaf(v, w_agg[k * 3 + 0], a0);
        a1 = fmaf(v, w_agg[k * 3 + 1], a1);
        a2 = fmaf(v, w_agg[k * 3 + 2], a2);
    }
    #pragma unroll
    for (int o = 32; o > 0; o >>= 1) {
        a0 += __shfl_xor(a0, o);
        a1 += __shfl_xor(a1, o);
        a2 += __shfl_xor(a2, o);
    }
    if (lane == 0) {
        y[b * 3 + 0] = fmaxf(a0, 0.f);
        y[b * 3 + 1] = fmaxf(a1, 0.f);
        y[b * 3 + 2] = fmaxf(a2, 0.f);
    }
}

extern "C" void kernel_launch(void* const* d_in, const int* in_sizes, int n_in,
                              void* d_out, int out_size, void* d_ws, size_t ws_size,
                              hipStream_t stream)
{
    (void)in_sizes; (void)n_in; (void)out_size; (void)ws_size;
    const int*   x1         = (const int*)d_in[0];
    const int*   x2         = (const int*)d_in[1];
    const float* emb        = (const float*)d_in[2];
    const float* w_intra    = (const float*)d_in[3];
    const float* bias_intra = (const float*)d_in[4];
    const float* w_proj1    = (const float*)d_in[5];
    const float* w_proj2    = (const float*)d_in[6];
    const float* w_att      = (const float*)d_in[7];
    const float* w_cmp1     = (const float*)d_in[8];
    const float* w_cmp2     = (const float*)d_in[9];
    const float* w_agg      = (const float*)d_in[10];
    float* y  = (float*)d_out;
    float* ws = (float*)d_ws;

    // ---- workspace (floats); total ~59.3M fl = 237.2 MB (< proven 240.4) ----
    float* X1CAT = ws;                        // [32768,400]: x1p | beta
    float* X2CAT = X1CAT + 13107200;          // [32768,400]: x2p | alpha
    float* T     = X2CAT + 13107200;          // [512,200,128]: G^T -> x_proj^T
    float* ATT   = T + 13107200;              // [512,128,128] probs; phase-B: SIMP|SMTP
    u16*   FBU16 = (u16*)(ATT + 8388608);     // f side1 [32768][320] u16 (pad 300:320 = 0)
    u16*   F1U16 = FBU16 + 10485760;          // f side2 [32768][320] u16
    u16*   F12U16= FBU16;                     // phase-B: f1|f2 [65536][224] u16 (f dead)
    float* POOL  = (float*)(F1U16 + 10485760);// [512,400] pooled v1|v2
    int*   SIZES = (int*)(POOL + 204800);
    float* NORMS = (float*)(SIZES + 512);     // [32000] + pad
    u16*   W1H   = (u16*)(NORMS + 32768);     // side-1 stack [556][320]: wp_b|z56|intra
    u16*   W1L   = W1H + 177920;
    u16*   W2H   = W1L + 177920;              // side-2 stack [556][320]
    u16*   W2L   = W2H + 177920;
    u16*   WAH   = W2L + 177920;              // w_att^T  [200][224]
    u16*   WAL   = WAH + 44800;
    u16*   WC1H  = WAL + 44800;               // w_cmp1^T [400][416]
    u16*   WC1L  = WC1H + 166400;
    u16*   WC2H  = WC1L + 166400;
    u16*   WC2L  = WC2H + 166400;
    u16*   WPA1H = WC2L + 166400;             // wp_a side1 [200][320]
    u16*   WPA1L = WPA1H + 64000;
    u16*   WPA2H = WPA1L + 64000;
    u16*   WPA2L = WPA2H + 64000;

    u16*   F2U16 = F12U16 + 32768 * 224;      // f2 half
    float* SIMP  = ATT;                       // [256,128,128] row-softmax probs
    float* SMTP  = ATT + 4194304;             // [256,128,128] col-softmax^T probs
    float* T1    = T;
    float* T2    = T + 6553600;

    const long long sbSS = (long long)SEQ * SEQ;     // 16384
    const long long sbF16= 128LL * 320;              // f slot stride (u16 units)
    const long long sbP16= 128LL * 224;              // f12 slot stride (u16 units)
    const long long sbC  = (long long)SEQ * 400;
    const long long sbT  = (long long)PDIM * SEQ;    // 25600

    sizes_kernel<<<dim3(BATCH, 2), 128, 0, stream>>>(x1, x2, SIZES);
    norms_kernel<<<32000, 64, 0, stream>>>(emb, NORMS);

    {
        WTab t;
        t.e[0]  = { w_proj1 + 300 * 200, W1H,             W1L,             300, 200, 320, 0    };
        t.e[1]  = { w_intra,             W1H + 200 * 320, W1L + 200 * 320,   0,  56, 320, 200  };
        t.e[2]  = { w_intra,             W1H + 256 * 320, W1L + 256 * 320, 300, 300, 320, 256  };
        t.e[3]  = { w_proj2 + 300 * 200, W2H,             W2L,             300, 200, 320, 556  };
        t.e[4]  = { w_intra,             W2H + 200 * 320, W2L + 200 * 320,   0,  56, 320, 756  };
        t.e[5]  = { w_intra,             W2H + 256 * 320, W2L + 256 * 320, 300, 300, 320, 812  };
        t.e[6]  = { w_att,               WAH,             WAL,             200, 200, 224, 1112 };
        t.e[7]  = { w_cmp1,              WC1H,            WC1L,            400, 400, 416, 1312 };
        t.e[8]  = { w_cmp2,              WC2H,            WC2L,            400, 400, 416, 1712 };
        t.e[9]  = { w_proj1,             WPA1H,           WPA1L,           300, 200, 320, 2112 };
        t.e[10] = { w_proj2,             WPA2H,           WPA2L,           300, 200, 320, 2312 };
        convert_all<<<dim3(2, 2512), 256, 0, stream>>>(t);
    }

    // -------- phase A --------
    // merged proj: T[0:512] = (e@wp_b)^T; f (u16 RNE) side1 -> FBU16, side2 -> F1U16
    gemm_proj<<<dim3(5, 512), 256, 0, stream>>>(
        x1, x2, emb, NORMS, W1H, W1L, W2H, W2L, T, FBU16, F1U16);
    // merged att (512 batches, 1-MFMA, u16 copy-staged): probs -> ATT
    gemm_bat<1, true><<<dim3(1, 1, 2 * BATCH), 256, 0, stream>>>(
        FBU16, F1U16, FBU16, nullptr, ATT, nullptr,
        SEQ, EDIM, 320, 320, 320, SEQ, sbF16, sbF16, sbSS, 0,
        0, bias_intra, nullptr, 1);
    // fused xp (3-MFMA): XCAT[:,0:200] = relu(e@wp_a + probs@G); x_proj^T -> T
    gemm_xp<<<dim3(2, 1, 2 * BATCH), 256, 0, stream>>>(
        ATT, T, x1, x2, emb, NORMS, WPA1H, WPA1L, WPA2H, WPA2L, X1CAT);

    // -------- phase B --------
    // f1|f2 = relu(x_proj @ w_att) -> u16 [65536][224] (pad 200:224 zeroed)
    gemm_flat<1><<<dim3(2, 512), 256, 0, stream>>>(
        X1CAT, WAH, WAL, WAH, WAL, 1 << 30,
        nullptr, F12U16, 224, 224, nullptr, nullptr,
        2 * BSTOK, PDIM, 224, 400, 224, PDIM, F_RELU);
    // fused sim (1-MFMA, u16 copy-staged): mask -> rowsm -> SIMP, colsm^T -> SMTP
    gemm_bat<2, true><<<dim3(1, 1, BATCH), 256, 0, stream>>>(
        F12U16, nullptr, F2U16, nullptr, SIMP, SMTP,
        SEQ, PDIM, 224, 224, 224, SEQ, sbP16, sbP16, sbSS, sbSS,
        0, nullptr, SIZES, 0);
    // beta (bz<256) / alpha (bz>=256) -> X1CAT/X2CAT cols 200:400  [3-MFMA fp32]
    gemm_bat<0, false><<<dim3(2, 1, 2 * BATCH), 256, 0, stream>>>(
        SIMP, SMTP, T2, T1, X1CAT + 200, nullptr,
        PDIM, SEQ, SEQ, SEQ, SEQ, 400, sbSS, sbT, sbC, 0,
        0, nullptr, nullptr, 0);

    // -------- phase C: fused compare + masked pool, aggregate [3-MFMA] --------
    gemm_flat<3><<<dim3(4, 512), 256, 0, stream>>>(
        X1CAT, WC1H, WC1L, WC2H, WC2L, BSTOK,
        nullptr, nullptr, 0, 0, POOL, SIZES,
        2 * BSTOK, 400, 416, 400, 416, 400, F_RELU);
    agg_kernel<<<BATCH, 64, 0, stream>>>(POOL, POOL + 102400, w_agg, y);
}